// Round 7
// baseline (252.779 us; speedup 1.0000x reference)
//
#include <hip/hip_runtime.h>
#include <stdint.h>
#include <math.h>

#define NH 16
#define DK 64
#define S_LEN 2048
#define BB 4
#define DM 1024
#define M_TOT (BB*S_LEN) // 8192
#define KVT 64
#define QB 128

// ---- GEMM geometry: 256x128 tile, BK=32, 8 waves (4M x 2N), triple-buffered LDS ----
// 72 KiB LDS/block -> 2 blocks/CU (16 waves, 4/SIMD) vs old BK=64's 144 KiB @ 1 block/CU.
#define BM 256
#define BN 128
#define BK 32
#define NTK (DM/BK)            // 32 K-tiles
#define LDS_A_BUF (BM*BK)      // 8192 ushort per buffer (16 KiB)
#define LDS_B_BUF (BN*BK)      // 4096 ushort per buffer (8 KiB)

typedef __attribute__((ext_vector_type(8))) short short8;
typedef __attribute__((ext_vector_type(4))) float floatx4;
typedef __attribute__((ext_vector_type(16))) float floatx16;

typedef const __attribute__((address_space(1))) void gas_t;
typedef __attribute__((address_space(3))) void las_t;

__device__ __forceinline__ void glds16(const void* g, void* l){
  __builtin_amdgcn_global_load_lds((gas_t*)g, (las_t*)l, 16, 0, 0);
}

// Sync primitives: inline-asm with "memory" clobber = compiler fence too.
#define VMCNT2() asm volatile("s_waitcnt vmcnt(2)" ::: "memory")
#define VMCNT3() asm volatile("s_waitcnt vmcnt(3)" ::: "memory")
#define VMCNT0() asm volatile("s_waitcnt vmcnt(0)" ::: "memory")
#define LGKM0()  do{ asm volatile("s_waitcnt lgkmcnt(0)" ::: "memory"); __builtin_amdgcn_sched_barrier(0); }while(0)
#define BARRIER() asm volatile("s_barrier" ::: "memory")
#define SCHEDB() __builtin_amdgcn_sched_barrier(0)

// v_permlane32_swap_b32 a, b: a's hi 32 lanes <-> b's lo 32 lanes.
#define PLSWAP(a, b) asm volatile("v_permlane32_swap_b32 %0, %1" : "+v"(a), "+v"(b))

__device__ __forceinline__ unsigned short f2bf(float f){
  unsigned int u = __float_as_uint(f);
  u += 0x7fffu + ((u >> 16) & 1u);
  return (unsigned short)(u >> 16);
}
// pack hi16(b):hi16(a) in one v_perm_b32 (truncation-rounded bf16 pair; a = low half)
__device__ __forceinline__ unsigned int pk_bf_trunc(float a, float b){
  return __builtin_amdgcn_perm(__float_as_uint(b), __float_as_uint(a), 0x07060302u);
}
__device__ __forceinline__ float fast_exp2(float x){
  return __builtin_amdgcn_exp2f(x);
}

// ---------------- cast fp32 -> bf16, all five tensors in ONE launch ----------------
__global__ void cast_all(const float* __restrict__ X,
                         const float* __restrict__ Wq, const float* __restrict__ Wk,
                         const float* __restrict__ Wv, const float* __restrict__ Wo,
                         unsigned short* __restrict__ Xb,
                         unsigned short* __restrict__ Wqb, unsigned short* __restrict__ Wkb,
                         unsigned short* __restrict__ Wvb, unsigned short* __restrict__ Wob)
{
  int b = blockIdx.x;
  const float* s;
  unsigned short* o;
  int base;
  if (b < 8192){ s = X; o = Xb; base = b; }
  else {
    int w = (b - 8192) >> 10;
    base = (b - 8192) & 1023;
    s = (w == 0) ? Wq : (w == 1) ? Wk : (w == 2) ? Wv : Wo;
    o = (w == 0) ? Wqb : (w == 1) ? Wkb : (w == 2) ? Wvb : Wob;
  }
  int i = base * 1024 + threadIdx.x * 4;
  float4 v = *(const float4*)(s + i);
  ushort4 u;
  u.x = f2bf(v.x); u.y = f2bf(v.y); u.z = f2bf(v.z); u.w = f2bf(v.w);
  *(ushort4*)(o + i) = u;
}

// ---- staging (BK=32): rows are 4 x 16B slots.  LDS dest lane-linear
// (global_load_lds requirement); source XOR-pre-swizzled so reads are
// conflict-free: phys slot p of row r holds logical slot p^((r>>1)&3).
// Read check: 8 consecutive lanes cover (row parity x 4 slots) = 32 banks.
__device__ __forceinline__ void stage_A(const unsigned short* __restrict__ A,
                                        int m0, int k0, unsigned short* As, int tid)
{
  #pragma unroll
  for (int j = 0; j < 2; j++){
    int c = j*512 + tid;                 // 1024 chunks = 256 rows x 4 slots
    int r = c >> 2;
    int sl = (c & 3) ^ ((r >> 1) & 3);
    glds16(&A[(size_t)(m0 + r)*DM + k0 + sl*8], (char*)As + (size_t)c*16);
  }
}
__device__ __forceinline__ void stage_B(const unsigned short* __restrict__ Bm,
                                        int n0, int k0, unsigned short* Bs, int tid)
{
  int c = tid;                           // 512 chunks = 128 rows x 4 slots
  int r = c >> 2;
  int sl = (c & 3) ^ ((r >> 1) & 3);
  glds16(&Bm[(size_t)(n0 + r)*DM + k0 + sl*8], (char*)Bs + (size_t)c*16);
}

// Triple-buffered, counted-vmcnt, 2-phase K-loop with register software
// pipelining.  Ledger (3 glds16/tile: A-part 2, B-part 1):
//  phase A(t): LGKM0 (drain B(t-1)'s frag reads); read a23(t); stage_A(t+2);
//              8 MFMA a01(t)xb(t); VMCNT(2) [t+1's 3 drained, t+2's 2 remain];
//              BARRIER [publishes buf t+1]
//  phase B(t): LGKM0 (a23 done); read a01(t+1)+b(t+1); stage_B(t+2);
//              8 MFMA a23(t)xb(t); BARRIER
// Buffer reuse safe: stage(t+2) targets buf (t-1)%3 whose reads completed
// before the barrier ending tile t-1.
__device__ __forceinline__ void gemm_core(const unsigned short* __restrict__ A,
                                          const unsigned short* __restrict__ Bm,
                                          int m0, int n0, unsigned short* Ls,
                                          int tid, floatx4 (&acc)[4][4])
{
  unsigned short* AsB = Ls;                   // 3 x LDS_A_BUF
  unsigned short* BsB = Ls + 3*LDS_A_BUF;     // 3 x LDS_B_BUF
  int wave = tid >> 6, lane = tid & 63;
  int l15 = lane & 15, quad = lane >> 4;
  int wm = (wave >> 1) * 64, wn = (wave & 1) * 64;
  int s0 = quad ^ ((l15 >> 1) & 3);           // phys slot of logical slot `quad`

  short8 a01[2], a23[2], b[2][4];             // b parity-indexed (live both phases)

  stage_A(A, m0, 0,  AsB, tid);             stage_B(Bm, n0, 0,  BsB, tid);
  stage_A(A, m0, BK, AsB + LDS_A_BUF, tid); stage_B(Bm, n0, BK, BsB + LDS_B_BUF, tid);
  VMCNT3();                                   // tile0's 3 landed; tile1's 3 in flight
  BARRIER();
  #pragma unroll
  for (int mi = 0; mi < 2; mi++)
    a01[mi] = *(const short8*)(AsB + (wm + mi*16 + l15)*BK + s0*8);
  #pragma unroll
  for (int ni = 0; ni < 4; ni++)
    b[0][ni] = *(const short8*)(BsB + (wn + ni*16 + l15)*BK + s0*8);

  #pragma unroll 2
  for (int t = 0; t < NTK; ++t){
    const int par = t & 1, nxt = par ^ 1;
    const unsigned short* Ab  = AsB + (t % 3)*LDS_A_BUF;
    const unsigned short* Abn = AsB + ((t+1) % 3)*LDS_A_BUF;
    const unsigned short* Bbn = BsB + ((t+1) % 3)*LDS_B_BUF;
    unsigned short* Ast = AsB + ((t+2) % 3)*LDS_A_BUF;
    unsigned short* Bst = BsB + ((t+2) % 3)*LDS_B_BUF;
    const int kst = (t + 2) * BK;

    // ---------------- phase A ----------------
    LGKM0();                                  // last phase's frag reads done
    #pragma unroll
    for (int mi = 0; mi < 2; mi++)
      a23[mi] = *(const short8*)(Ab + (wm + (2+mi)*16 + l15)*BK + s0*8);
    if (t + 2 < NTK) stage_A(A, m0, kst, Ast, tid);
    SCHEDB();
    __builtin_amdgcn_s_setprio(1);
    #pragma unroll
    for (int mi = 0; mi < 2; mi++)
      #pragma unroll
      for (int ni = 0; ni < 4; ni++)
        acc[mi][ni] = __builtin_amdgcn_mfma_f32_16x16x32_bf16(a01[mi], b[par][ni], acc[mi][ni], 0, 0, 0);
    __builtin_amdgcn_s_setprio(0);
    if (t + 2 < NTK)      { VMCNT2(); }       // drain t+1's 3; t+2's A-part 2 remain
    else if (t + 1 < NTK) { VMCNT0(); }       // tail: drain last tile fully
    BARRIER();                                // publishes buf t+1

    // ---------------- phase B ----------------
    LGKM0();                                  // a23 reads done
    if (t + 1 < NTK){
      #pragma unroll
      for (int mi = 0; mi < 2; mi++)
        a01[mi] = *(const short8*)(Abn + (wm + mi*16 + l15)*BK + s0*8);
      #pragma unroll
      for (int ni = 0; ni < 4; ni++)
        b[nxt][ni] = *(const short8*)(Bbn + (wn + ni*16 + l15)*BK + s0*8);
    }
    if (t + 2 < NTK) stage_B(Bm, n0, kst, Bst, tid);
    SCHEDB();
    __builtin_amdgcn_s_setprio(1);
    #pragma unroll
    for (int mi = 0; mi < 2; mi++)
      #pragma unroll
      for (int ni = 0; ni < 4; ni++)
        acc[2+mi][ni] = __builtin_amdgcn_mfma_f32_16x16x32_bf16(a23[mi], b[par][ni], acc[2+mi][ni], 0, 0, 0);
    __builtin_amdgcn_s_setprio(0);
    if (t + 1 < NTK) BARRIER();
  }
}

// ---------------- QKV GEMM with fused RoPE (Q,K) and transposed-V epilogue ----------------
__global__ __launch_bounds__(512, 4) void gemm_qkv(
    const unsigned short* __restrict__ Xb,
    const unsigned short* __restrict__ Wq,
    const unsigned short* __restrict__ Wk,
    const unsigned short* __restrict__ Wv,
    const int* __restrict__ pos,
    unsigned short* __restrict__ Qo,
    unsigned short* __restrict__ Ko,
    unsigned short* __restrict__ VTo)
{
  __shared__ __align__(16) unsigned short Ls[3*LDS_A_BUF + 3*LDS_B_BUF];  // 72 KiB
  int m0 = blockIdx.x * BM;
  int n0 = blockIdx.y * BN;
  int z  = blockIdx.z;
  const unsigned short* Bmat = (z == 0) ? Wq : ((z == 1) ? Wk : Wv);
  unsigned short* Out = (z == 0) ? Qo : ((z == 1) ? Ko : VTo);

  int tid = threadIdx.x;
  floatx4 acc[4][4] = {};
  gemm_core(Xb, Bmat, m0, n0, Ls, tid, acc);

  int wave = tid >> 6, lane = tid & 63;
  int l15 = lane & 15, quad = lane >> 4;
  int wm = (wave >> 1) * 64, wn = (wave & 1) * 64;

  if (z == 2){
    #pragma unroll
    for (int mi = 0; mi < 4; mi++){
      int row0 = m0 + wm + mi * 16 + quad * 4;
      int bb2 = row0 >> 11, sQ = row0 & (S_LEN - 1);
      #pragma unroll
      for (int ni = 0; ni < 4; ni++){
        int col = n0 + wn + ni * 16 + l15;
        int h = col >> 6, d = col & 63;
        ushort4 u;
        u.x = f2bf(acc[mi][ni][0]); u.y = f2bf(acc[mi][ni][1]);
        u.z = f2bf(acc[mi][ni][2]); u.w = f2bf(acc[mi][ni][3]);
        *(ushort4*)&Out[(((size_t)bb2 * NH + h) * DK + d) * S_LEN + sQ] = u;
      }
    }
  } else {
    // RoPE via hardware v_sin/v_cos (revolutions): no libm calls -> no spills.
    const float SC = (z == 0) ? 0.180336879f : 1.0f;   // 0.125 * log2(e) for Q
    #pragma unroll
    for (int mi = 0; mi < 4; mi++){
      #pragma unroll
      for (int ni = 0; ni < 4; ni++){
        int col = n0 + wn + ni * 16 + l15;
        int h = col >> 6, d = col & 63;
        int fi = d >> 1, odd = d & 1;
        float invfrev = fast_exp2(-(float)fi * (13.2877123795494f / 32.0f)) * 0.15915494309f;
        #pragma unroll
        for (int r = 0; r < 4; r++){
          int row = m0 + wm + mi * 16 + quad * 4 + r;
          int bb2 = row >> 11, s = row & (S_LEN - 1);
          float p = (float)pos[s];
          float rev = p * invfrev;
          rev = rev - floorf(rev);
          float c  = __builtin_amdgcn_cosf(rev);
          float sn = __builtin_amdgcn_sinf(rev);
          float val = acc[mi][ni][r];
          float other = __shfl_xor(val, 1);
          float outv = odd ? (other * sn + val * c) : (val * c - other * sn);
          Out[(((size_t)bb2 * NH + h) * S_LEN + s) * DK + d] = f2bf(outv * SC);
        }
      }
    }
  }
}

// ---------------- Output projection GEMM: fp32 out ----------------
__global__ __launch_bounds__(512, 4) void gemm_out(
    const unsigned short* __restrict__ Ab,
    const unsigned short* __restrict__ Wo,
    float* __restrict__ Out)
{
  __shared__ __align__(16) unsigned short Ls[3*LDS_A_BUF + 3*LDS_B_BUF];
  int m0 = blockIdx.x * BM;
  int n0 = blockIdx.y * BN;

  int tid = threadIdx.x;
  floatx4 acc[4][4] = {};
  gemm_core(Ab, Wo, m0, n0, Ls, tid, acc);

  int wave = tid >> 6, lane = tid & 63;
  int l15 = lane & 15, quad = lane >> 4;
  int wm = (wave >> 1) * 64, wn = (wave & 1) * 64;

  #pragma unroll
  for (int mi = 0; mi < 4; mi++){
    #pragma unroll
    for (int ni = 0; ni < 4; ni++){
      #pragma unroll
      for (int r = 0; r < 4; r++){
        int row = m0 + wm + mi * 16 + quad * 4 + r;
        int col = n0 + wn + ni * 16 + l15;
        Out[(size_t)row * DM + col] = acc[mi][ni][r];
      }
    }
  }
}

// ---------------- Flash attention (causal), 32x32 swapped-operand, in-reg P ----
// (round-6 version, unchanged: 65.5 -> ~50us win)
__global__ __launch_bounds__(256, 3) void attn_kernel(
    const unsigned short* __restrict__ Qg,
    const unsigned short* __restrict__ Kg,
    const unsigned short* __restrict__ VTg,
    unsigned short* __restrict__ Ao)
{
  __shared__ __align__(16) unsigned short Ks[2][KVT * 64];   // [buf][kv][dk], slots XORed
  __shared__ __align__(16) unsigned short Vs[2][DK * 64];    // [buf][d][kv],  slots XORed

  int bh = blockIdx.x;
  int q0 = ((int)gridDim.y - 1 - (int)blockIdx.y) * QB;   // heavy-first
  int tid = threadIdx.x, wave = tid >> 6, lane = tid & 63;
  int l31 = lane & 31, hi = lane >> 5;
  int qw = q0 + wave * 32;
  int qg = qw + l31;                     // this lane's q row

  const unsigned short* Qb = Qg + (size_t)bh * S_LEN * DK;
  const unsigned short* Kb = Kg + (size_t)bh * S_LEN * DK;
  const unsigned short* Vb = VTg + (size_t)bh * DK * S_LEN;

  // Q B-operand frags: B[k][q]: lane holds Q[q=l31][kc*16 + hi*8 .. +7]
  short8 qf[4];
  #pragma unroll
  for (int kc = 0; kc < 4; kc++)
    qf[kc] = *(const short8*)&Qb[(size_t)qg * DK + kc * 16 + hi * 8];

  floatx16 oA = {0.f,0.f,0.f,0.f,0.f,0.f,0.f,0.f,0.f,0.f,0.f,0.f,0.f,0.f,0.f,0.f};
  floatx16 oB = {0.f,0.f,0.f,0.f,0.f,0.f,0.f,0.f,0.f,0.f,0.f,0.f,0.f,0.f,0.f,0.f};
  float lsum = 0.f;

  // per-lane LDS read element offsets for the 4 k-chunks (K and V share them)
  int e7 = l31 & 7;
  int eoff[4];
  #pragma unroll
  for (int kc = 0; kc < 4; kc++)
    eoff[kc] = l31 * 64 + (((kc * 2 + hi) ^ e7) * 8);

  // staging: thread (srow, sj) covers row srow, 16B slots 2sj, 2sj+1 (swizzled)
  int srow = tid >> 2, sj = tid & 3;
  const unsigned short* Krow = Kb + (size_t)srow * DK + sj * 16;
  const unsigned short* Vrow = Vb + (size_t)srow * S_LEN + sj * 16;
  int ws0 = (((2 * sj)     ^ (srow & 7)) * 8) + srow * 64;
  int ws1 = (((2 * sj + 1) ^ (srow & 7)) * 8) + srow * 64;

  int nt = q0 / KVT + 2;

  // prefetch tile 0
  short8 kr0 = *(const short8*)(Krow);
  short8 kr1 = *(const short8*)(Krow + 8);
  short8 vr0 = *(const short8*)(Vrow);
  short8 vr1 = *(const short8*)(Vrow + 8);

  for (int kt = 0; kt < nt; kt++){
    int kv0 = kt * KVT;
    int p = kt & 1;
    *(short8*)&Ks[p][ws0] = kr0;
    *(short8*)&Ks[p][ws1] = kr1;
    *(short8*)&Vs[p][ws0] = vr0;
    *(short8*)&Vs[p][ws1] = vr1;
    if (kt + 1 < nt){                    // prefetch next tile (hides under compute)
      int kvn = kv0 + KVT;
      kr0 = *(const short8*)(Krow + (size_t)kvn * DK);
      kr1 = *(const short8*)(Krow + (size_t)kvn * DK + 8);
      vr0 = *(const short8*)(Vrow + kvn);
      vr1 = *(const short8*)(Vrow + kvn + 8);
    }
    LGKM0();                             // own ds_writes done
    BARRIER();                           // tile published; one barrier per tile

    #pragma unroll
    for (int sub = 0; sub < 2; sub++){
      int kvs = kv0 + sub * 32;
      if (kvs <= qw + 31){               // wave-uniform
        bool subfull = (kvs + 31 <= qw);
        // ---- QK^T swapped ----
        floatx16 s16 = {0.f,0.f,0.f,0.f,0.f,0.f,0.f,0.f,0.f,0.f,0.f,0.f,0.f,0.f,0.f,0.f};
        #pragma unroll
        for (int kc = 0; kc < 4; kc++){
          short8 kf = *(const short8*)&Ks[p][sub * 2048 + eoff[kc]];
          s16 = __builtin_amdgcn_mfma_f32_32x32x16_bf16(kf, qf[kc], s16, 0, 0, 0);
        }
        // ---- softmax (no-max): mask, exp2, pack ----
        unsigned int u[8];
        float ls = 0.f;
        #pragma unroll
        for (int j = 0; j < 8; j++){
          int row0 = ((2*j) & 3) + 8 * ((2*j) >> 2) + 4 * hi;  // kv row of reg 2j
          float v0 = s16[2*j], v1 = s16[2*j+1];
          if (!subfull){
            v0 = (kvs + row0     > qg) ? -INFINITY : v0;
            v1 = (kvs + row0 + 1 > qg) ? -INFINITY : v1;
          }
          float p0 = fast_exp2(v0);
          float p1 = fast_exp2(v1);
          ls += p0 + p1;
          u[j] = pk_bf_trunc(p0, p1);
        }
        lsum += ls;
        // ---- half-wave exchange: u[2i] <-> u[2i+2] ----
        PLSWAP(u[0], u[2]); PLSWAP(u[1], u[3]);
        PLSWAP(u[4], u[6]); PLSWAP(u[5], u[7]);
        union { unsigned int w[4]; short8 v; } c0, c1;
        c0.w[0] = u[0]; c0.w[1] = u[1]; c0.w[2] = u[2]; c0.w[3] = u[3];
        c1.w[0] = u[4]; c1.w[1] = u[5]; c1.w[2] = u[6]; c1.w[3] = u[7];
        // ---- PV for this sub: kv chunks sub*2, sub*2+1 ----
        short8 vf0 = *(const short8*)&Vs[p][eoff[sub*2]];
        short8 vf1 = *(const short8*)&Vs[p][eoff[sub*2+1]];
        short8 vf2 = *(const short8*)&Vs[p][2048 + eoff[sub*2]];
        short8 vf3 = *(const short8*)&Vs[p][2048 + eoff[sub*2+1]];
        oA = __builtin_amdgcn_mfma_f32_32x32x16_bf16(vf0, c0.v, oA, 0, 0, 0);
        oA = __builtin_amdgcn_mfma_f32_32x32x16_bf16(vf1, c1.v, oA, 0, 0, 0);
        oB = __builtin_amdgcn_mfma_f32_32x32x16_bf16(vf2, c0.v, oB, 0, 0, 0);
        oB = __builtin_amdgcn_mfma_f32_32x32x16_bf16(vf3, c1.v, oB, 0, 0, 0);
      }
    }
  }

  // each half-wave summed 32 of 64 kv for its q; combine
  float rs = lsum + __shfl_xor(lsum, 32);
  float linv = 1.0f / rs;

  int bq = bh >> 4, hq = bh & 15;
  size_t obase = (((size_t)bq * S_LEN + qg) * NH + hq) * DK;
  #pragma unroll
  for (int g = 0; g < 4; g++){
    int d0 = 8 * g + 4 * hi;
    ushort4 ua, ub;
    ua.x = f2bf(oA[4*g+0] * linv); ua.y = f2bf(oA[4*g+1] * linv);
    ua.z = f2bf(oA[4*g+2] * linv); ua.w = f2bf(oA[4*g+3] * linv);
    ub.x = f2bf(oB[4*g+0] * linv); ub.y = f2bf(oB[4*g+1] * linv);
    ub.z = f2bf(oB[4*g+2] * linv); ub.w = f2bf(oB[4*g+3] * linv);
    *(ushort4*)&Ao[obase + d0]      = ua;
    *(ushort4*)&Ao[obase + 32 + d0] = ub;
  }
}

extern "C" void kernel_launch(void* const* d_in, const int* in_sizes, int n_in,
                              void* d_out, int out_size, void* d_ws, size_t ws_size,
                              hipStream_t stream) {
  (void)in_sizes; (void)n_in; (void)out_size; (void)ws_size;
  const float* Wq = (const float*)d_in[0];
  const float* Wk = (const float*)d_in[1];
  const float* Wv = (const float*)d_in[2];
  const float* Wo = (const float*)d_in[3];
  const float* X  = (const float*)d_in[4];
  const int* pos  = (const int*)d_in[5];
  float* out = (float*)d_out;

  char* ws = (char*)d_ws;
  const size_t MB = 1024 * 1024;
  unsigned short* Xb  = (unsigned short*)(ws);             // 16 MB
  unsigned short* Wqb = (unsigned short*)(ws + 16 * MB);   // 2 MB
  unsigned short* Wkb = (unsigned short*)(ws + 18 * MB);
  unsigned short* Wvb = (unsigned short*)(ws + 20 * MB);
  unsigned short* Wob = (unsigned short*)(ws + 22 * MB);
  unsigned short* Qb  = (unsigned short*)(ws + 24 * MB);   // 16 MB
  unsigned short* Kb  = (unsigned short*)(ws + 40 * MB);
  unsigned short* Vb  = (unsigned short*)(ws + 56 * MB);   // transposed [bh][dk][S]
  unsigned short* Ab  = (unsigned short*)(ws + 72 * MB);

  cast_all<<<12288, 256, 0, stream>>>(X, Wq, Wk, Wv, Wo, Xb, Wqb, Wkb, Wvb, Wob);

  gemm_qkv<<<dim3(M_TOT/BM, DM/BN, 3), 512, 0, stream>>>(Xb, Wqb, Wkb, Wvb, pos, Qb, Kb, Vb);
  attn_kernel<<<dim3(64, S_LEN / QB), 256, 0, stream>>>(Qb, Kb, Vb, Ab);
  gemm_out<<<dim3(M_TOT/BM, DM/BN), 512, 0, stream>>>(Ab, Wob, out);
}

// Round 8
// 219.876 us; speedup vs baseline: 1.1496x; 1.1496x over previous
//
#include <hip/hip_runtime.h>
#include <stdint.h>
#include <math.h>

#define NH 16
#define DK 64
#define S_LEN 2048
#define BB 4
#define DM 1024
#define M_TOT (BB*S_LEN) // 8192
#define KVT 64
#define QB 128

// ---- GEMM geometry: 256x128 tile, BK=64, 8 waves (4M x 2N), triple-buffered LDS ----
// NOTE (R7): BK=32 @ 2 blocks/CU regressed 60->83us (barrier count doubled, 8-MFMA
// phases too short to amortize sync).  BK=64 @ 1 block/CU is the proven point.
#define BM 256
#define BN 128
#define BK 64
#define NTK (DM/BK)            // 16 K-tiles
#define LDS_A_BUF (BM*BK)      // 16384 ushort per buffer
#define LDS_B_BUF (BN*BK)      // 8192 ushort per buffer

typedef __attribute__((ext_vector_type(8))) short short8;
typedef __attribute__((ext_vector_type(4))) float floatx4;
typedef __attribute__((ext_vector_type(16))) float floatx16;

typedef const __attribute__((address_space(1))) void gas_t;
typedef __attribute__((address_space(3))) void las_t;

__device__ __forceinline__ void glds16(const void* g, void* l){
  __builtin_amdgcn_global_load_lds((gas_t*)g, (las_t*)l, 16, 0, 0);
}

// Sync primitives: inline-asm with "memory" clobber = compiler fence too.
#define VMCNT3() asm volatile("s_waitcnt vmcnt(3)" ::: "memory")
#define VMCNT6() asm volatile("s_waitcnt vmcnt(6)" ::: "memory")
#define VMCNT0() asm volatile("s_waitcnt vmcnt(0)" ::: "memory")
#define LGKM0()  do{ asm volatile("s_waitcnt lgkmcnt(0)" ::: "memory"); __builtin_amdgcn_sched_barrier(0); }while(0)
#define BARRIER() asm volatile("s_barrier" ::: "memory")
#define SCHEDB() __builtin_amdgcn_sched_barrier(0)

// v_permlane32_swap_b32 a, b: a's hi 32 lanes <-> b's lo 32 lanes.
#define PLSWAP(a, b) asm volatile("v_permlane32_swap_b32 %0, %1" : "+v"(a), "+v"(b))

__device__ __forceinline__ unsigned short f2bf(float f){
  unsigned int u = __float_as_uint(f);
  u += 0x7fffu + ((u >> 16) & 1u);
  return (unsigned short)(u >> 16);
}
// pack hi16(b):hi16(a) in one v_perm_b32 (truncation-rounded bf16 pair; a = low half)
__device__ __forceinline__ unsigned int pk_bf_trunc(float a, float b){
  return __builtin_amdgcn_perm(__float_as_uint(b), __float_as_uint(a), 0x07060302u);
}
__device__ __forceinline__ float fast_exp2(float x){
  return __builtin_amdgcn_exp2f(x);
}

// ---------------- cast fp32 -> bf16, all five tensors in ONE launch ----------------
__global__ void cast_all(const float* __restrict__ X,
                         const float* __restrict__ Wq, const float* __restrict__ Wk,
                         const float* __restrict__ Wv, const float* __restrict__ Wo,
                         unsigned short* __restrict__ Xb,
                         unsigned short* __restrict__ Wqb, unsigned short* __restrict__ Wkb,
                         unsigned short* __restrict__ Wvb, unsigned short* __restrict__ Wob)
{
  int b = blockIdx.x;
  const float* s;
  unsigned short* o;
  int base;
  if (b < 8192){ s = X; o = Xb; base = b; }
  else {
    int w = (b - 8192) >> 10;
    base = (b - 8192) & 1023;
    s = (w == 0) ? Wq : (w == 1) ? Wk : (w == 2) ? Wv : Wo;
    o = (w == 0) ? Wqb : (w == 1) ? Wkb : (w == 2) ? Wvb : Wob;
  }
  int i = base * 1024 + threadIdx.x * 4;
  float4 v = *(const float4*)(s + i);
  ushort4 u;
  u.x = f2bf(v.x); u.y = f2bf(v.y); u.z = f2bf(v.z); u.w = f2bf(v.w);
  *(ushort4*)(o + i) = u;
}

// Stage half of one K-tile (3 x glds16).  LDS dest lane-linear; source XOR-
// pre-swizzled (slot p of row r holds logical slot p^(r&7)). Conflict-free.
__device__ __forceinline__ void stage_part(const unsigned short* __restrict__ A,
                                           const unsigned short* __restrict__ Bm,
                                           int m0, int n0, int k0,
                                           unsigned short* As, unsigned short* Bs,
                                           int tid, int part)
{
  if (part == 0){
    #pragma unroll
    for (int j = 0; j < 2; j++){
      int c = j*512 + tid;
      int r = c >> 3;
      int sl = (c & 7) ^ (r & 7);
      glds16(&A[(size_t)(m0 + r)*DM + k0 + sl*8], (char*)As + (size_t)c*16);
    }
    int c = tid;
    int r = c >> 3;
    int sl = (c & 7) ^ (r & 7);
    glds16(&Bm[(size_t)(n0 + r)*DM + k0 + sl*8], (char*)Bs + (size_t)c*16);
  } else {
    #pragma unroll
    for (int j = 2; j < 4; j++){
      int c = j*512 + tid;
      int r = c >> 3;
      int sl = (c & 7) ^ (r & 7);
      glds16(&A[(size_t)(m0 + r)*DM + k0 + sl*8], (char*)As + (size_t)c*16);
    }
    int c = 512 + tid;
    int r = c >> 3;
    int sl = (c & 7) ^ (r & 7);
    glds16(&Bm[(size_t)(n0 + r)*DM + k0 + sl*8], (char*)Bs + (size_t)c*16);
  }
}

// Triple-buffered, counted-vmcnt, phase-interleaved K-loop with register
// software pipelining (round-6 proven form; k-chained MFMA order).
__device__ __forceinline__ void gemm_core(const unsigned short* __restrict__ A,
                                          const unsigned short* __restrict__ Bm,
                                          int m0, int n0, unsigned short* Ls,
                                          int tid, floatx4 (&acc)[4][4])
{
  unsigned short* AsB = Ls;                   // 3 x LDS_A_BUF
  unsigned short* BsB = Ls + 3*LDS_A_BUF;     // 3 x LDS_B_BUF
  int wave = tid >> 6, lane = tid & 63;
  int l15 = lane & 15, quad = lane >> 4;
  int wm = (wave >> 1) * 64, wn = (wave & 1) * 64;
  int s0 = quad ^ (l15 & 7);                  // swizzled slot for kk=0; kk=1 is s0^4

  short8 a01[2][2], a23[2][2], b[2][4][2];

  stage_part(A, Bm, m0, n0, 0,  AsB,             BsB,             tid, 0);
  stage_part(A, Bm, m0, n0, 0,  AsB,             BsB,             tid, 1);
  stage_part(A, Bm, m0, n0, BK, AsB + LDS_A_BUF, BsB + LDS_B_BUF, tid, 0);
  stage_part(A, Bm, m0, n0, BK, AsB + LDS_A_BUF, BsB + LDS_B_BUF, tid, 1);
  VMCNT6();
  BARRIER();
  #pragma unroll
  for (int mi = 0; mi < 2; mi++){
    const unsigned short* pr = AsB + (wm + mi*16 + l15)*BK;
    a01[mi][0] = *(const short8*)(pr + s0*8);
    a01[mi][1] = *(const short8*)(pr + (s0^4)*8);
  }
  #pragma unroll
  for (int ni = 0; ni < 4; ni++){
    const unsigned short* pr = BsB + (wn + ni*16 + l15)*BK;
    b[0][ni][0] = *(const short8*)(pr + s0*8);
    b[0][ni][1] = *(const short8*)(pr + (s0^4)*8);
  }

  #pragma unroll
  for (int t = 0; t < NTK; ++t){
    const int par = t & 1, nxt = par ^ 1;
    const unsigned short* Ab  = AsB + (t % 3)*LDS_A_BUF;
    const unsigned short* Abn = AsB + ((t+1) % 3)*LDS_A_BUF;
    const unsigned short* Bbn = BsB + ((t+1) % 3)*LDS_B_BUF;
    unsigned short* Ast = AsB + ((t+2) % 3)*LDS_A_BUF;
    unsigned short* Bst = BsB + ((t+2) % 3)*LDS_B_BUF;
    const int kst = (t + 2) * BK;

    // ---------------- phase A ----------------
    LGKM0();
    #pragma unroll
    for (int mi = 0; mi < 2; mi++){
      const unsigned short* pr = Ab + (wm + (2+mi)*16 + l15)*BK;
      a23[mi][0] = *(const short8*)(pr + s0*8);
      a23[mi][1] = *(const short8*)(pr + (s0^4)*8);
    }
    if (t + 2 < NTK) stage_part(A, Bm, m0, n0, kst, Ast, Bst, tid, 0);
    SCHEDB();
    __builtin_amdgcn_s_setprio(1);
    #pragma unroll
    for (int mi = 0; mi < 2; mi++)
      #pragma unroll
      for (int ni = 0; ni < 4; ni++){
        acc[mi][ni] = __builtin_amdgcn_mfma_f32_16x16x32_bf16(a01[mi][0], b[par][ni][0], acc[mi][ni], 0, 0, 0);
        acc[mi][ni] = __builtin_amdgcn_mfma_f32_16x16x32_bf16(a01[mi][1], b[par][ni][1], acc[mi][ni], 0, 0, 0);
      }
    __builtin_amdgcn_s_setprio(0);
    if (t + 2 < NTK)      { VMCNT3(); }
    else if (t + 1 < NTK) { VMCNT0(); }
    BARRIER();

    // ---------------- phase B ----------------
    LGKM0();
    if (t + 1 < NTK){
      #pragma unroll
      for (int mi = 0; mi < 2; mi++){
        const unsigned short* pr = Abn + (wm + mi*16 + l15)*BK;
        a01[mi][0] = *(const short8*)(pr + s0*8);
        a01[mi][1] = *(const short8*)(pr + (s0^4)*8);
      }
      #pragma unroll
      for (int ni = 0; ni < 4; ni++){
        const unsigned short* pr = Bbn + (wn + ni*16 + l15)*BK;
        b[nxt][ni][0] = *(const short8*)(pr + s0*8);
        b[nxt][ni][1] = *(const short8*)(pr + (s0^4)*8);
      }
    }
    if (t + 2 < NTK) stage_part(A, Bm, m0, n0, kst, Ast, Bst, tid, 1);
    SCHEDB();
    __builtin_amdgcn_s_setprio(1);
    #pragma unroll
    for (int mi = 0; mi < 2; mi++)
      #pragma unroll
      for (int ni = 0; ni < 4; ni++){
        acc[2+mi][ni] = __builtin_amdgcn_mfma_f32_16x16x32_bf16(a23[mi][0], b[par][ni][0], acc[2+mi][ni], 0, 0, 0);
        acc[2+mi][ni] = __builtin_amdgcn_mfma_f32_16x16x32_bf16(a23[mi][1], b[par][ni][1], acc[2+mi][ni], 0, 0, 0);
      }
    __builtin_amdgcn_s_setprio(0);
    if (t + 1 < NTK) BARRIER();
  }
}

// ---------------- QKV GEMM with fused RoPE (Q,K) and transposed-V epilogue ----------------
__global__ __launch_bounds__(512, 2) void gemm_qkv(
    const unsigned short* __restrict__ Xb,
    const unsigned short* __restrict__ Wq,
    const unsigned short* __restrict__ Wk,
    const unsigned short* __restrict__ Wv,
    const int* __restrict__ pos,
    unsigned short* __restrict__ Qo,
    unsigned short* __restrict__ Ko,
    unsigned short* __restrict__ VTo)
{
  __shared__ __align__(16) unsigned short Ls[3*LDS_A_BUF + 3*LDS_B_BUF];  // 144 KiB
  int m0 = blockIdx.x * BM;
  int n0 = blockIdx.y * BN;
  int z  = blockIdx.z;
  const unsigned short* Bmat = (z == 0) ? Wq : ((z == 1) ? Wk : Wv);
  unsigned short* Out = (z == 0) ? Qo : ((z == 1) ? Ko : VTo);

  int tid = threadIdx.x;
  floatx4 acc[4][4] = {};
  gemm_core(Xb, Bmat, m0, n0, Ls, tid, acc);

  int wave = tid >> 6, lane = tid & 63;
  int l15 = lane & 15, quad = lane >> 4;
  int wm = (wave >> 1) * 64, wn = (wave & 1) * 64;

  if (z == 2){
    #pragma unroll
    for (int mi = 0; mi < 4; mi++){
      int row0 = m0 + wm + mi * 16 + quad * 4;
      int bb2 = row0 >> 11, sQ = row0 & (S_LEN - 1);
      #pragma unroll
      for (int ni = 0; ni < 4; ni++){
        int col = n0 + wn + ni * 16 + l15;
        int h = col >> 6, d = col & 63;
        ushort4 u;
        u.x = f2bf(acc[mi][ni][0]); u.y = f2bf(acc[mi][ni][1]);
        u.z = f2bf(acc[mi][ni][2]); u.w = f2bf(acc[mi][ni][3]);
        *(ushort4*)&Out[(((size_t)bb2 * NH + h) * DK + d) * S_LEN + sQ] = u;
      }
    }
  } else {
    // RoPE via hardware v_sin/v_cos (revolutions): no libm calls -> no spills.
    const float SC = (z == 0) ? 0.180336879f : 1.0f;   // 0.125 * log2(e) for Q
    #pragma unroll
    for (int mi = 0; mi < 4; mi++){
      #pragma unroll
      for (int ni = 0; ni < 4; ni++){
        int col = n0 + wn + ni * 16 + l15;
        int h = col >> 6, d = col & 63;
        int fi = d >> 1, odd = d & 1;
        float invfrev = fast_exp2(-(float)fi * (13.2877123795494f / 32.0f)) * 0.15915494309f;
        #pragma unroll
        for (int r = 0; r < 4; r++){
          int row = m0 + wm + mi * 16 + quad * 4 + r;
          int bb2 = row >> 11, s = row & (S_LEN - 1);
          float p = (float)pos[s];
          float rev = p * invfrev;
          rev = rev - floorf(rev);
          float c  = __builtin_amdgcn_cosf(rev);
          float sn = __builtin_amdgcn_sinf(rev);
          float val = acc[mi][ni][r];
          float other = __shfl_xor(val, 1);
          float outv = odd ? (other * sn + val * c) : (val * c - other * sn);
          Out[(((size_t)bb2 * NH + h) * S_LEN + s) * DK + d] = f2bf(outv * SC);
        }
      }
    }
  }
}

// ---------------- Output projection GEMM: fp32 out ----------------
__global__ __launch_bounds__(512, 2) void gemm_out(
    const unsigned short* __restrict__ Ab,
    const unsigned short* __restrict__ Wo,
    float* __restrict__ Out)
{
  __shared__ __align__(16) unsigned short Ls[3*LDS_A_BUF + 3*LDS_B_BUF];
  int m0 = blockIdx.x * BM;
  int n0 = blockIdx.y * BN;

  int tid = threadIdx.x;
  floatx4 acc[4][4] = {};
  gemm_core(Ab, Wo, m0, n0, Ls, tid, acc);

  int wave = tid >> 6, lane = tid & 63;
  int l15 = lane & 15, quad = lane >> 4;
  int wm = (wave >> 1) * 64, wn = (wave & 1) * 64;

  #pragma unroll
  for (int mi = 0; mi < 4; mi++){
    #pragma unroll
    for (int ni = 0; ni < 4; ni++){
      #pragma unroll
      for (int r = 0; r < 4; r++){
        int row = m0 + wm + mi * 16 + quad * 4 + r;
        int col = n0 + wn + ni * 16 + l15;
        Out[(size_t)row * DM + col] = acc[mi][ni][r];
      }
    }
  }
}

// ---------------- Flash attention (causal), 32x32 swapped-operand, in-reg P ----
// R7 change: launch_bounds 3 -> 4 blocks/CU (LDS 32KB x 4 = 128KB fits; VGPR
// cap 128).  Extra wave/SIMD covers the serial softmax chain between MFMAs.
__global__ __launch_bounds__(256, 4) void attn_kernel(
    const unsigned short* __restrict__ Qg,
    const unsigned short* __restrict__ Kg,
    const unsigned short* __restrict__ VTg,
    unsigned short* __restrict__ Ao)
{
  __shared__ __align__(16) unsigned short Ks[2][KVT * 64];   // [buf][kv][dk], slots XORed
  __shared__ __align__(16) unsigned short Vs[2][DK * 64];    // [buf][d][kv],  slots XORed

  int bh = blockIdx.x;
  int q0 = ((int)gridDim.y - 1 - (int)blockIdx.y) * QB;   // heavy-first
  int tid = threadIdx.x, wave = tid >> 6, lane = tid & 63;
  int l31 = lane & 31, hi = lane >> 5;
  int qw = q0 + wave * 32;
  int qg = qw + l31;                     // this lane's q row

  const unsigned short* Qb = Qg + (size_t)bh * S_LEN * DK;
  const unsigned short* Kb = Kg + (size_t)bh * S_LEN * DK;
  const unsigned short* Vb = VTg + (size_t)bh * DK * S_LEN;

  // Q B-operand frags: B[k][q]: lane holds Q[q=l31][kc*16 + hi*8 .. +7]
  short8 qf[4];
  #pragma unroll
  for (int kc = 0; kc < 4; kc++)
    qf[kc] = *(const short8*)&Qb[(size_t)qg * DK + kc * 16 + hi * 8];

  floatx16 oA = {0.f,0.f,0.f,0.f,0.f,0.f,0.f,0.f,0.f,0.f,0.f,0.f,0.f,0.f,0.f,0.f};
  floatx16 oB = {0.f,0.f,0.f,0.f,0.f,0.f,0.f,0.f,0.f,0.f,0.f,0.f,0.f,0.f,0.f,0.f};
  float lsum = 0.f;

  // per-lane LDS read element offsets for the 4 k-chunks (K and V share them)
  int e7 = l31 & 7;
  int eoff[4];
  #pragma unroll
  for (int kc = 0; kc < 4; kc++)
    eoff[kc] = l31 * 64 + (((kc * 2 + hi) ^ e7) * 8);

  // staging: thread (srow, sj) covers row srow, 16B slots 2sj, 2sj+1 (swizzled)
  int srow = tid >> 2, sj = tid & 3;
  const unsigned short* Krow = Kb + (size_t)srow * DK + sj * 16;
  const unsigned short* Vrow = Vb + (size_t)srow * S_LEN + sj * 16;
  int ws0 = (((2 * sj)     ^ (srow & 7)) * 8) + srow * 64;
  int ws1 = (((2 * sj + 1) ^ (srow & 7)) * 8) + srow * 64;

  int nt = q0 / KVT + 2;

  // prefetch tile 0
  short8 kr0 = *(const short8*)(Krow);
  short8 kr1 = *(const short8*)(Krow + 8);
  short8 vr0 = *(const short8*)(Vrow);
  short8 vr1 = *(const short8*)(Vrow + 8);

  for (int kt = 0; kt < nt; kt++){
    int kv0 = kt * KVT;
    int p = kt & 1;
    *(short8*)&Ks[p][ws0] = kr0;
    *(short8*)&Ks[p][ws1] = kr1;
    *(short8*)&Vs[p][ws0] = vr0;
    *(short8*)&Vs[p][ws1] = vr1;
    if (kt + 1 < nt){                    // prefetch next tile (hides under compute)
      int kvn = kv0 + KVT;
      kr0 = *(const short8*)(Krow + (size_t)kvn * DK);
      kr1 = *(const short8*)(Krow + (size_t)kvn * DK + 8);
      vr0 = *(const short8*)(Vrow + kvn);
      vr1 = *(const short8*)(Vrow + kvn + 8);
    }
    LGKM0();                             // own ds_writes done
    BARRIER();                           // tile published; one barrier per tile

    #pragma unroll
    for (int sub = 0; sub < 2; sub++){
      int kvs = kv0 + sub * 32;
      if (kvs <= qw + 31){               // wave-uniform
        bool subfull = (kvs + 31 <= qw);
        // ---- QK^T swapped ----
        floatx16 s16 = {0.f,0.f,0.f,0.f,0.f,0.f,0.f,0.f,0.f,0.f,0.f,0.f,0.f,0.f,0.f,0.f};
        #pragma unroll
        for (int kc = 0; kc < 4; kc++){
          short8 kf = *(const short8*)&Ks[p][sub * 2048 + eoff[kc]];
          s16 = __builtin_amdgcn_mfma_f32_32x32x16_bf16(kf, qf[kc], s16, 0, 0, 0);
        }
        // ---- softmax (no-max): mask, exp2, pack ----
        unsigned int u[8];
        float ls = 0.f;
        #pragma unroll
        for (int j = 0; j < 8; j++){
          int row0 = ((2*j) & 3) + 8 * ((2*j) >> 2) + 4 * hi;  // kv row of reg 2j
          float v0 = s16[2*j], v1 = s16[2*j+1];
          if (!subfull){
            v0 = (kvs + row0     > qg) ? -INFINITY : v0;
            v1 = (kvs + row0 + 1 > qg) ? -INFINITY : v1;
          }
          float p0 = fast_exp2(v0);
          float p1 = fast_exp2(v1);
          ls += p0 + p1;
          u[j] = pk_bf_trunc(p0, p1);
        }
        lsum += ls;
        // ---- half-wave exchange: u[2i] <-> u[2i+2] ----
        PLSWAP(u[0], u[2]); PLSWAP(u[1], u[3]);
        PLSWAP(u[4], u[6]); PLSWAP(u[5], u[7]);
        union { unsigned int w[4]; short8 v; } c0, c1;
        c0.w[0] = u[0]; c0.w[1] = u[1]; c0.w[2] = u[2]; c0.w[3] = u[3];
        c1.w[0] = u[4]; c1.w[1] = u[5]; c1.w[2] = u[6]; c1.w[3] = u[7];
        // ---- PV for this sub: kv chunks sub*2, sub*2+1 ----
        short8 vf0 = *(const short8*)&Vs[p][eoff[sub*2]];
        short8 vf1 = *(const short8*)&Vs[p][eoff[sub*2+1]];
        short8 vf2 = *(const short8*)&Vs[p][2048 + eoff[sub*2]];
        short8 vf3 = *(const short8*)&Vs[p][2048 + eoff[sub*2+1]];
        oA = __builtin_amdgcn_mfma_f32_32x32x16_bf16(vf0, c0.v, oA, 0, 0, 0);
        oA = __builtin_amdgcn_mfma_f32_32x32x16_bf16(vf1, c1.v, oA, 0, 0, 0);
        oB = __builtin_amdgcn_mfma_f32_32x32x16_bf16(vf2, c0.v, oB, 0, 0, 0);
        oB = __builtin_amdgcn_mfma_f32_32x32x16_bf16(vf3, c1.v, oB, 0, 0, 0);
      }
    }
  }

  // each half-wave summed 32 of 64 kv for its q; combine
  float rs = lsum + __shfl_xor(lsum, 32);
  float linv = 1.0f / rs;

  int bq = bh >> 4, hq = bh & 15;
  size_t obase = (((size_t)bq * S_LEN + qg) * NH + hq) * DK;
  #pragma unroll
  for (int g = 0; g < 4; g++){
    int d0 = 8 * g + 4 * hi;
    ushort4 ua, ub;
    ua.x = f2bf(oA[4*g+0] * linv); ua.y = f2bf(oA[4*g+1] * linv);
    ua.z = f2bf(oA[4*g+2] * linv); ua.w = f2bf(oA[4*g+3] * linv);
    ub.x = f2bf(oB[4*g+0] * linv); ub.y = f2bf(oB[4*g+1] * linv);
    ub.z = f2bf(oB[4*g+2] * linv); ub.w = f2bf(oB[4*g+3] * linv);
    *(ushort4*)&Ao[obase + d0]      = ua;
    *(ushort4*)&Ao[obase + 32 + d0] = ub;
  }
}

extern "C" void kernel_launch(void* const* d_in, const int* in_sizes, int n_in,
                              void* d_out, int out_size, void* d_ws, size_t ws_size,
                              hipStream_t stream) {
  (void)in_sizes; (void)n_in; (void)out_size; (void)ws_size;
  const float* Wq = (const float*)d_in[0];
  const float* Wk = (const float*)d_in[1];
  const float* Wv = (const float*)d_in[2];
  const float* Wo = (const float*)d_in[3];
  const float* X  = (const float*)d_in[4];
  const int* pos  = (const int*)d_in[5];
  float* out = (float*)d_out;

  char* ws = (char*)d_ws;
  const size_t MB = 1024 * 1024;
  unsigned short* Xb  = (unsigned short*)(ws);             // 16 MB
  unsigned short* Wqb = (unsigned short*)(ws + 16 * MB);   // 2 MB
  unsigned short* Wkb = (unsigned short*)(ws + 18 * MB);
  unsigned short* Wvb = (unsigned short*)(ws + 20 * MB);
  unsigned short* Wob = (unsigned short*)(ws + 22 * MB);
  unsigned short* Qb  = (unsigned short*)(ws + 24 * MB);   // 16 MB
  unsigned short* Kb  = (unsigned short*)(ws + 40 * MB);
  unsigned short* Vb  = (unsigned short*)(ws + 56 * MB);   // transposed [bh][dk][S]
  unsigned short* Ab  = (unsigned short*)(ws + 72 * MB);

  cast_all<<<12288, 256, 0, stream>>>(X, Wq, Wk, Wv, Wo, Xb, Wqb, Wkb, Wvb, Wob);

  gemm_qkv<<<dim3(M_TOT/BM, DM/BN, 3), 512, 0, stream>>>(Xb, Wqb, Wkb, Wvb, pos, Qb, Kb, Vb);
  attn_kernel<<<dim3(64, S_LEN / QB), 256, 0, stream>>>(Qb, Kb, Vb, Ab);
  gemm_out<<<dim3(M_TOT/BM, DM/BN), 512, 0, stream>>>(Ab, Wob, out);
}